// Round 5
// baseline (955.568 us; speedup 1.0000x reference)
//
#include <hip/hip_runtime.h>

// QLSTM: B=512, T=1024, IN=1, H=64.
// One wave (64 threads) per batch element, grid 512 -> 2 waves/CU.
// Lane l owns unit l AND all four gate rows {l, 64+l, 128+l, 192+l}:
//   - i,f,g,o for unit l are computed in-lane  -> NO cross-lane gather
//   - c_l, h_l update is in-lane               -> NO barrier, NO shfl
// The only cross-lane traffic is the h all-gather, done as LDS write (1 op)
// + 16 broadcast ds_read_b128 per step, double-buffered (no WAR hazard),
// all within one wave -> no __syncthreads in the loop at all.
// Weights: 4 rows x 64 = 256 fp32/lane as 128 v2f -> v_pk_fma_f32 stream
// (128/step) in 8 independent chains; overflow lives in AGPRs (unified file,
// VALU reads AGPR operands directly on CDNA).

typedef float v2f __attribute__((ext_vector_type(2)));

#define TLEN 1024
#define HID  64

__device__ __forceinline__ float fast_sigmoid(float x) {
    return __builtin_amdgcn_rcpf(1.0f + __expf(-x));   // hw exp + hw rcp
}
__device__ __forceinline__ float fast_tanh(float x) {
    return __builtin_fmaf(2.0f, fast_sigmoid(2.0f * x), -1.0f);
}

__global__ __launch_bounds__(64, 1)
void qlstm_kernel(const float* __restrict__ x,      // [B, T, 1]
                  const float* __restrict__ W_ih,   // [256, 1]
                  const float* __restrict__ W_hh,   // [256, 64]
                  const float* __restrict__ b_ih,   // [256]
                  const float* __restrict__ b_hh,   // [256]
                  const float* __restrict__ W_lin,  // [1, 64]
                  const float* __restrict__ b_lin,  // [1]
                  float* __restrict__ out)          // [B]
{
    const int b = blockIdx.x;
    const int l = threadIdx.x;   // 0..63 = hidden unit

    __shared__ __align__(16) float xs[TLEN];      // 4 KB
    __shared__ __align__(16) float hs[2][HID];    // double-buffered h

    // Stage x row (coalesced, 4 float4 per lane).
    const float4* xsrc = (const float4*)(x + (size_t)b * TLEN);
    #pragma unroll
    for (int q = 0; q < 4; ++q)
        ((float4*)xs)[q * 64 + l] = xsrc[q * 64 + l];

    // All 4 gate rows for unit l: 256 weights as 128 v2f.
    v2f wv[4][32];
    float u[4], bias[4];
    #pragma unroll
    for (int g = 0; g < 4; ++g) {
        const int row = g * HID + l;
        const v2f* Wr = (const v2f*)(W_hh + (size_t)row * HID);
        #pragma unroll
        for (int q = 0; q < 32; ++q) wv[g][q] = Wr[q];
        u[g]    = W_ih[row];                      // IN == 1
        bias[g] = b_ih[row] + b_hh[row];
    }

    float c = 0.0f, h = 0.0f;
    hs[0][l] = 0.0f;
    __syncthreads();   // once, before the loop (single wave: cheap)

    auto step = [&](int t, const float* __restrict__ hin,
                    float* __restrict__ hout) {
        const float xt = xs[t];                   // same-address broadcast
        v2f a0[4], a1[4];
        #pragma unroll
        for (int g = 0; g < 4; ++g) {
            a0[g].x = __builtin_fmaf(xt, u[g], bias[g]);
            a0[g].y = 0.0f;
            a1[g].x = 0.0f; a1[g].y = 0.0f;
        }
        const float4* hp = (const float4*)hin;    // 16 broadcast b128 reads
        #pragma unroll
        for (int q = 0; q < 16; ++q) {
            const float4 hq = hp[q];
            const v2f hA = {hq.x, hq.y};
            const v2f hB = {hq.z, hq.w};
            #pragma unroll
            for (int g = 0; g < 4; ++g) {         // 8 independent chains
                a0[g] = __builtin_elementwise_fma(hA, wv[g][2 * q + 0], a0[g]);
                a1[g] = __builtin_elementwise_fma(hB, wv[g][2 * q + 1], a1[g]);
            }
        }
        float gate[4];
        #pragma unroll
        for (int g = 0; g < 4; ++g) {
            const v2f s = a0[g] + a1[g];          // v_pk_add_f32
            gate[g] = s.x + s.y;
        }
        const float ig = fast_sigmoid(gate[0]);
        const float fg = fast_sigmoid(gate[1]);
        const float gg = fast_tanh(gate[2]);      // independent -> overlap
        const float og = fast_sigmoid(gate[3]);
        c = __builtin_fmaf(fg, c, ig * gg);
        h = og * fast_tanh(c);
        hout[l] = h;                              // 1 ds_write_b32
    };

    for (int t = 0; t < TLEN; t += 2) {
        step(t,     hs[0], hs[1]);
        step(t + 1, hs[1], hs[0]);
    }

    // out[b] = dot(h_final, W_lin) + b_lin  (h_final in registers, lane l).
    float v = h * W_lin[l];
    #pragma unroll
    for (int off = 32; off > 0; off >>= 1)
        v += __shfl_down(v, off, 64);
    if (l == 0) out[b] = v + b_lin[0];
}

extern "C" void kernel_launch(void* const* d_in, const int* in_sizes, int n_in,
                              void* d_out, int out_size, void* d_ws, size_t ws_size,
                              hipStream_t stream) {
    const float* x     = (const float*)d_in[0];
    const float* W_ih  = (const float*)d_in[1];
    const float* W_hh  = (const float*)d_in[2];
    const float* b_ih  = (const float*)d_in[3];
    const float* b_hh  = (const float*)d_in[4];
    const float* W_lin = (const float*)d_in[5];
    const float* b_lin = (const float*)d_in[6];
    float* out = (float*)d_out;

    const int B = out_size;  // 512
    qlstm_kernel<<<B, 64, 0, stream>>>(x, W_ih, W_hh, b_ih, b_hh, W_lin, b_lin, out);
}

// Round 6
// 771.005 us; speedup vs baseline: 1.2394x; 1.2394x over previous
//
#include <hip/hip_runtime.h>

// QLSTM: B=512, T=1024, IN=1, H=64.
// KEY INSIGHT from rounds 2-4: all structures stalled at ~1400 cyc/step =
// 128 broadcast ds_read_b128 per CU per step (LDS-pipe throughput, ~11 cyc
// each). h is WAVE-UNIFORM data -> move it to SGPRs (64 v_readlane/step) and
// feed v_pk_fma_f32 with an SGPR-pair src0, op_sel-broadcasting one h value
// to both halves. LDS traffic per step collapses to one b64 write + one b64
// read per wave.
//
// Layout: 2 waves per batch element (block=128, grid=512 -> 4 waves/CU).
// Wave w owns gates {2w, 2w+1} (i,f | g,o) for ALL 64 units; lane l = unit l.
// Weights gate-interleaved: wg2[k] = {W_hh[(2w)*64+l][k], W_hh[(2w+1)*64+l][k]}
// -> 64 v2f = 128 VGPRs (fits arch VGPRs; round 5's v2f array at 256 floats
// spilled to scratch -- 128 floats stays clear of the cliff).
// One pk_fma per k does BOTH gates: acc.{x,y} += h_k * wg2[k].{x,y}.
// Exchange: each wave publishes its 2 activations (b64, double-buffered),
// ONE barrier, both waves redundantly update c,h in-lane. h never touches LDS.

typedef float v2f __attribute__((ext_vector_type(2)));

#define TLEN 1024
#define HID  64

__device__ __forceinline__ float fast_sigmoid(float x) {
    return __builtin_amdgcn_rcpf(1.0f + __expf(-x));   // hw exp + hw rcp
}
__device__ __forceinline__ float fast_tanh(float x) {
    return __builtin_fmaf(2.0f, fast_sigmoid(2.0f * x), -1.0f);
}

__global__ __launch_bounds__(128, 1)
void qlstm_kernel(const float* __restrict__ x,      // [B, T, 1]
                  const float* __restrict__ W_ih,   // [256, 1]
                  const float* __restrict__ W_hh,   // [256, 64]
                  const float* __restrict__ b_ih,   // [256]
                  const float* __restrict__ b_hh,   // [256]
                  const float* __restrict__ W_lin,  // [1, 64]
                  const float* __restrict__ b_lin,  // [1]
                  float* __restrict__ out)          // [B]
{
    const int b   = blockIdx.x;
    const int tid = threadIdx.x;
    const int w   = tid >> 6;        // wave 0 -> gates i,f ; wave 1 -> g,o
    const int l   = tid & 63;        // unit

    __shared__ __align__(16) float  xs[TLEN];        // 4 KB
    __shared__ __align__(8)  float2 axc[2][2][HID];  // [parity][wave][unit]

    // Stage x row: 1024 floats, two float4 per thread.
    {
        const float4* xsrc = (const float4*)(x + (size_t)b * TLEN);
        ((float4*)xs)[tid]       = xsrc[tid];
        ((float4*)xs)[128 + tid] = xsrc[128 + tid];
    }

    // Gate-interleaved weight pairs for this lane's two rows.
    const int r0 = (2 * w) * HID + l;        // gate 2w
    const int r1 = (2 * w + 1) * HID + l;    // gate 2w+1
    v2f wg2[64];
    {
        const float4* p0 = (const float4*)(W_hh + (size_t)r0 * HID);
        const float4* p1 = (const float4*)(W_hh + (size_t)r1 * HID);
        #pragma unroll
        for (int k4 = 0; k4 < 16; ++k4) {
            const float4 a = p0[k4];
            const float4 c4 = p1[k4];
            wg2[4 * k4 + 0] = (v2f){a.x, c4.x};
            wg2[4 * k4 + 1] = (v2f){a.y, c4.y};
            wg2[4 * k4 + 2] = (v2f){a.z, c4.z};
            wg2[4 * k4 + 3] = (v2f){a.w, c4.w};
        }
    }

    const v2f u2    = (v2f){W_ih[r0], W_ih[r1]};                   // IN == 1
    const v2f bias2 = (v2f){b_ih[r0] + b_hh[r0], b_ih[r1] + b_hh[r1]};
    const float wlin = W_lin[l];

    // Wave-uniform activation constants for component .x (gate g is tanh).
    const float sA = (w == 1) ? 2.0f : 1.0f;
    const float mA = (w == 1) ? 2.0f : 1.0f;
    const float dA = (w == 1) ? -1.0f : 0.0f;

    float c = 0.0f, h = 0.0f;
    __syncthreads();   // xs ready

    for (int t = 0; t < TLEN; ++t) {
        const int p = t & 1;
        const float xt = xs[t];                    // same-address broadcast

        // h (per-lane) -> SGPR pairs via readlane; hp[q] = {h_2q, h_2q+1}.
        const int hbits = __float_as_int(h);
        v2f hp[32];
        #pragma unroll
        for (int q = 0; q < 32; ++q) {
            hp[q].x = __int_as_float(__builtin_amdgcn_readlane(hbits, 2 * q));
            hp[q].y = __int_as_float(__builtin_amdgcn_readlane(hbits, 2 * q + 1));
        }

        // acc.{x,y} = rows {r0,r1} . h  -- 64 pk_fma, SGPR h broadcast via
        // op_sel (src0 low/high half replicated to both lanes of the op).
        v2f a0 = {0.0f, 0.0f}, a1 = {0.0f, 0.0f};
        v2f a2 = {0.0f, 0.0f}, a3 = {0.0f, 0.0f};
        #pragma unroll
        for (int q = 0; q < 32; q += 2) {
            asm("v_pk_fma_f32 %0, %1, %2, %0 op_sel:[0,0,0] op_sel_hi:[0,1,1]"
                : "+v"(a0) : "s"(hp[q]),     "v"(wg2[2 * q + 0]));
            asm("v_pk_fma_f32 %0, %1, %2, %0 op_sel:[1,0,0] op_sel_hi:[1,1,1]"
                : "+v"(a1) : "s"(hp[q]),     "v"(wg2[2 * q + 1]));
            asm("v_pk_fma_f32 %0, %1, %2, %0 op_sel:[0,0,0] op_sel_hi:[0,1,1]"
                : "+v"(a2) : "s"(hp[q + 1]), "v"(wg2[2 * q + 2]));
            asm("v_pk_fma_f32 %0, %1, %2, %0 op_sel:[1,0,0] op_sel_hi:[1,1,1]"
                : "+v"(a3) : "s"(hp[q + 1]), "v"(wg2[2 * q + 3]));
        }
        v2f gate = (a0 + a1) + (a2 + a3);
        gate.x = __builtin_fmaf(xt, u2.x, gate.x + bias2.x);
        gate.y = __builtin_fmaf(xt, u2.y, gate.y + bias2.y);

        // Activations (wave-uniform constants, no divergence).
        const float ax = __builtin_fmaf(mA, fast_sigmoid(sA * gate.x), dA);
        const float ay = fast_sigmoid(gate.y);

        // Exchange the 2 activations; ONE barrier; redundant c/h update.
        axc[p][w][l] = make_float2(ax, ay);        // ds_write_b64, 2-way ok
        __syncthreads();
        const float2 oth = axc[p][w ^ 1][l];       // ds_read_b64
        const float ig = w ? oth.x : ax;
        const float fg = w ? oth.y : ay;
        const float gg = w ? ax   : oth.x;
        const float og = w ? ay   : oth.y;
        c = __builtin_fmaf(fg, c, ig * gg);
        h = og * fast_tanh(c);                     // stays in registers
    }

    // out[b] = dot(h, W_lin) + b_lin  (wave 0 only).
    if (w == 0) {
        float v = h * wlin;
        #pragma unroll
        for (int off = 32; off > 0; off >>= 1)
            v += __shfl_down(v, off, 64);
        if (l == 0) out[b] = v + b_lin[0];
    }
}

extern "C" void kernel_launch(void* const* d_in, const int* in_sizes, int n_in,
                              void* d_out, int out_size, void* d_ws, size_t ws_size,
                              hipStream_t stream) {
    const float* x     = (const float*)d_in[0];
    const float* W_ih  = (const float*)d_in[1];
    const float* W_hh  = (const float*)d_in[2];
    const float* b_ih  = (const float*)d_in[3];
    const float* b_hh  = (const float*)d_in[4];
    const float* W_lin = (const float*)d_in[5];
    const float* b_lin = (const float*)d_in[6];
    float* out = (float*)d_out;

    const int B = out_size;  // 512
    qlstm_kernel<<<B, 128, 0, stream>>>(x, W_ih, W_hh, b_ih, b_hh, W_lin, b_lin, out);
}

// Round 7
// 668.151 us; speedup vs baseline: 1.4302x; 1.1539x over previous
//
#include <hip/hip_runtime.h>

// QLSTM: B=512, T=1024, IN=1, H=64.
// Round-7 structure: quad-K-split + DPP quad reduction.
//   block = 128 (2 waves per sequence), grid = 512 -> 2 blocks/CU.
//   wave w owns gates {2w, 2w+1}  (w0: i,f   w1: g,o).
//   lane l: quad q=l>>2, pos p=l&3. Owns units 4q..4q+3 (so unit==lane after
//   selection) over K-chunk [16p, 16p+16).
// Weights: 8 outputs (4 units x 2 gates) x 8 K-pairs = 64 v2f (128 VGPRs),
//   K-pair packed -> v_pk_fma_f32 with src0 = adjacent h pair (no splat, no
//   inline asm, no SGPR h, no readlane).
// h delivery: 4 ds_read_b128 per wave (lane reads its 16-float K-chunk from a
//   per-wave PRIVATE double-buffered hs copy; 16 lanes/address broadcast,
//   2-way bank alias = free). Partial sums reduced across the quad with
//   mov_dpp quad_perm (VALU pipe, zero DS traffic).
// Exchange: each wave publishes its 2 activations (1 ds_write_b64,
//   double-buffered), ONE barrier, redundant c/h update in both waves,
//   private h write (no second barrier).

typedef float v2f __attribute__((ext_vector_type(2)));

#define TLEN 1024
#define HID  64

__device__ __forceinline__ float fast_sigmoid(float x) {
    return __builtin_amdgcn_rcpf(1.0f + __expf(-x));   // hw exp + hw rcp
}
__device__ __forceinline__ float fast_tanh(float x) {
    return __builtin_fmaf(2.0f, fast_sigmoid(2.0f * x), -1.0f);
}
// Sum across the 4 lanes of a quad (quad_perm xor1 then xor2) - VALU only.
__device__ __forceinline__ float quad_sum(float v) {
    v += __int_as_float(__builtin_amdgcn_mov_dpp(__float_as_int(v), 0xB1, 0xF, 0xF, false));
    v += __int_as_float(__builtin_amdgcn_mov_dpp(__float_as_int(v), 0x4E, 0xF, 0xF, false));
    return v;
}

__global__ __launch_bounds__(128, 1)
void qlstm_kernel(const float* __restrict__ x,      // [B, T, 1]
                  const float* __restrict__ W_ih,   // [256, 1]
                  const float* __restrict__ W_hh,   // [256, 64]
                  const float* __restrict__ b_ih,   // [256]
                  const float* __restrict__ b_hh,   // [256]
                  const float* __restrict__ W_lin,  // [1, 64]
                  const float* __restrict__ b_lin,  // [1]
                  float* __restrict__ out)          // [B]
{
    const int b   = blockIdx.x;
    const int tid = threadIdx.x;
    const int w   = tid >> 6;        // wave: 0 -> i,f   1 -> g,o
    const int l   = tid & 63;        // unit
    const int p   = l & 3;           // K-chunk id
    const int q4  = l & ~3;          // base unit of this lane's quad (4q)
    const int k0  = p << 4;          // K-chunk start (16p)

    __shared__ __align__(16) float  xs[TLEN];         // 4 KB
    __shared__ __align__(16) float  hs[2][2][HID];    // [wave][parity][unit]
    __shared__ __align__(8)  float2 gp[2][2][HID];    // [parity][wave][unit]

    // Stage x row: 1024 floats, two float4 per thread.
    {
        const float4* xsrc = (const float4*)(x + (size_t)b * TLEN);
        ((float4*)xs)[tid]       = xsrc[tid];
        ((float4*)xs)[128 + tid] = xsrc[128 + tid];
    }

    // Weights: out o = u4*2 + gi -> row (2w+gi)*64 + (q4+u4), K-pairs from
    // this lane's chunk. 64 v2f = 128 VGPRs.
    v2f wv[8][8];
    #pragma unroll
    for (int u4 = 0; u4 < 4; ++u4) {
        #pragma unroll
        for (int gi = 0; gi < 2; ++gi) {
            const int r = (2 * w + gi) * HID + q4 + u4;
            const float4* pr = (const float4*)(W_hh + (size_t)r * HID + k0);
            const int o = u4 * 2 + gi;
            #pragma unroll
            for (int j = 0; j < 4; ++j) {
                const float4 f = pr[j];
                wv[o][2 * j]     = (v2f){f.x, f.y};
                wv[o][2 * j + 1] = (v2f){f.z, f.w};
            }
        }
    }

    const int r0 = (2 * w) * HID + l;
    const int r1 = (2 * w + 1) * HID + l;
    const float u0 = W_ih[r0], u1 = W_ih[r1];                  // IN == 1
    const float bias0 = b_ih[r0] + b_hh[r0];
    const float bias1 = b_ih[r1] + b_hh[r1];

    // Wave-uniform activation constants for gate0 (wave1's gate0 = g = tanh).
    const float sA = (w == 1) ? 2.0f : 1.0f;
    const float mA = (w == 1) ? 2.0f : 1.0f;
    const float dA = (w == 1) ? -1.0f : 0.0f;

    float c = 0.0f, h = 0.0f;
    hs[w][0][l] = 0.0f;            // private copy, parity 0
    __syncthreads();               // xs staged

    auto step = [&](int t, int par) {
        const float xt = xs[t];                       // broadcast b32

        // Lane's 16-float h chunk from the PRIVATE copy (4 b128, broadcast
        // within 16-lane groups, 2-way bank alias = free).
        const float4* hp4 = (const float4*)&hs[w][par][k0];
        const float4 h0 = hp4[0], h1 = hp4[1], h2 = hp4[2], h3 = hp4[3];
        const v2f hk[8] = {{h0.x, h0.y}, {h0.z, h0.w}, {h1.x, h1.y}, {h1.z, h1.w},
                           {h2.x, h2.y}, {h2.z, h2.w}, {h3.x, h3.y}, {h3.z, h3.w}};

        // 64 v_pk_fma_f32: 8 outputs x 8 K-pairs, 8 independent chains.
        v2f acc[8] = {{0.f, 0.f}, {0.f, 0.f}, {0.f, 0.f}, {0.f, 0.f},
                      {0.f, 0.f}, {0.f, 0.f}, {0.f, 0.f}, {0.f, 0.f}};
        #pragma unroll
        for (int k2 = 0; k2 < 8; ++k2) {
            #pragma unroll
            for (int o = 0; o < 8; ++o)
                acc[o] = __builtin_elementwise_fma(hk[k2], wv[o][k2], acc[o]);
        }

        // Horizontal add then quad reduction (VALU DPP, no LDS).
        float s[8];
        #pragma unroll
        for (int o = 0; o < 8; ++o) s[o] = quad_sum(acc[o].x + acc[o].y);

        // Select this lane's own unit (u4 == p): o = u4*2 + gi.
        const float t0a = (p & 1) ? s[2] : s[0];
        const float t0b = (p & 1) ? s[6] : s[4];
        const float m0  = (p & 2) ? t0b : t0a;
        const float t1a = (p & 1) ? s[3] : s[1];
        const float t1b = (p & 1) ? s[7] : s[5];
        const float m1  = (p & 2) ? t1b : t1a;

        const float gg0 = __builtin_fmaf(xt, u0, m0 + bias0);
        const float gg1 = __builtin_fmaf(xt, u1, m1 + bias1);

        // Activations (wave-uniform constants, no divergence).
        const float a0 = __builtin_fmaf(mA, fast_sigmoid(sA * gg0), dA);
        const float a1 = fast_sigmoid(gg1);

        // Exchange the 2 activations; ONE barrier; redundant c/h update.
        gp[par][w][l] = make_float2(a0, a1);          // ds_write_b64
        __syncthreads();
        const float2 oth = gp[par][w ^ 1][l];         // ds_read_b64
        const float ig  = w ? oth.x : a0;
        const float fg  = w ? oth.y : a1;
        const float ggt = w ? a0    : oth.x;
        const float og  = w ? a1    : oth.y;
        c = __builtin_fmaf(fg, c, ig * ggt);
        h = og * fast_tanh(c);
        hs[w][par ^ 1][l] = h;                        // private; no barrier
    };

    for (int t = 0; t < TLEN; t += 2) {
        step(t, 0);
        step(t + 1, 1);
    }

    // out[b] = dot(h, W_lin) + b_lin  (wave 0 only; h_l lives in lane l).
    if (w == 0) {
        float v = h * W_lin[l];
        #pragma unroll
        for (int off = 32; off > 0; off >>= 1)
            v += __shfl_down(v, off, 64);
        if (l == 0) out[b] = v + b_lin[0];
    }
}

extern "C" void kernel_launch(void* const* d_in, const int* in_sizes, int n_in,
                              void* d_out, int out_size, void* d_ws, size_t ws_size,
                              hipStream_t stream) {
    const float* x     = (const float*)d_in[0];
    const float* W_ih  = (const float*)d_in[1];
    const float* W_hh  = (const float*)d_in[2];
    const float* b_ih  = (const float*)d_in[3];
    const float* b_hh  = (const float*)d_in[4];
    const float* W_lin = (const float*)d_in[5];
    const float* b_lin = (const float*)d_in[6];
    float* out = (float*)d_out;

    const int B = out_size;  // 512
    qlstm_kernel<<<B, 128, 0, stream>>>(x, W_ih, W_hh, b_ih, b_hh, W_lin, b_lin, out);
}